// Round 2
// baseline (260.258 us; speedup 1.0000x reference)
//
#include <hip/hip_runtime.h>
#include <hip/hip_bf16.h>
#include <stdint.h>

#define NSTEP   32
#define BATCH   65536
#define NTHR    512
#define RPH     128          /* rows per half = 8 waves x 16 */
#define DELTA_F (1.0f/32.0f)
#define LN2PI_F 1.83787706640934534f

// R21: W2 register-cache (R20 idea) + PINNED occupancy. R20 spilled because
// dynamic-LDS hides the 1-block/CU cap from the compiler and launch_bounds(,2)
// is only a lower bound -> regalloc targeted 4 waves/EU (128-reg budget) and
// dumped the 128-reg w2r array to scratch (WRITE_SIZE 0.26->18.7 MB).
// amdgpu_waves_per_eu(2,2) pins exactly 2 waves/EU -> 256-reg budget -> fits.
#define RB      272
#define OFF_W1  0            /* W1^T [128 nu][136] u16 (b1 baked @ k=80) */
#define OFF_W2  34816        /* W2^T [128 nu][136] u16 (staged once, reg-cached) */
#define OFF_W3  69632        /* W3comb [16 m][136] u16 */
#define OFF_W8  73984        /* f32[128]: W1 row 80 (t coefficient) */
#define OFF_B2  74496        /* f32[128]: b2 */
#define OFF_WB  75008        /* 8 waves x [16 r][136] transpose buffers (4352 B each) */
#define LDS_BYTES 109824     /* 1 block/CU */

typedef __attribute__((ext_vector_type(8))) short    s16x8;
typedef __attribute__((ext_vector_type(8))) __bf16   bf16x8;
typedef __attribute__((ext_vector_type(4))) float    f32x4;
typedef __attribute__((ext_vector_type(4))) int      i32x4;
typedef __attribute__((ext_vector_type(4))) unsigned u32x4;
typedef __attribute__((ext_vector_type(2))) unsigned u32x2;

static __device__ __forceinline__ f32x4 mfma16(s16x8 a, s16x8 b, f32x4 c){
    return __builtin_amdgcn_mfma_f32_16x16x32_bf16(
        __builtin_bit_cast(bf16x8, a), __builtin_bit_cast(bf16x8, b), c, 0, 0, 0);
}

static __device__ __forceinline__ unsigned short f2bf(float f){
    union { float f; unsigned u; } v; v.f = f;
    unsigned u = v.u + 0x7fffu + ((v.u >> 16) & 1u);   // RNE
    return (unsigned short)(u >> 16);
}

static __device__ __forceinline__ unsigned cvtpk(float lo, float hi){
    unsigned r;
    asm("v_cvt_pk_bf16_f32 %0, %1, %2" : "=v"(r) : "v"(lo), "v"(hi));
    return r;
}

static __device__ __forceinline__ s16x8 pconv(i32x4 u0, i32x4 u1){
    const unsigned P = 0x3F80u, M = 0xBF80u;
    u32x4 d;
    d[0] = (u0[0] ? P : M) | ((u0[1] ? P : M) << 16);
    d[1] = (u0[2] ? P : M) | ((u0[3] ? P : M) << 16);
    d[2] = (u1[0] ? P : M) | ((u1[1] ? P : M) << 16);
    d[3] = (u1[2] ? P : M) | ((u1[3] ? P : M) << 16);
    return __builtin_bit_cast(s16x8, d);
}

static __device__ __forceinline__ void relu_pack(f32x4 pre, f32x4 tan, u32x2* H, u32x2* T){
    float h0 = pre[0]>0.f?pre[0]:0.f, h1 = pre[1]>0.f?pre[1]:0.f;
    float h2 = pre[2]>0.f?pre[2]:0.f, h3 = pre[3]>0.f?pre[3]:0.f;
    float s0 = pre[0]>0.f?tan[0]:0.f, s1 = pre[1]>0.f?tan[1]:0.f;
    float s2 = pre[2]>0.f?tan[2]:0.f, s3 = pre[3]>0.f?tan[3]:0.f;
    H->x = cvtpk(h0,h1); H->y = cvtpk(h2,h3);
    T->x = cvtpk(s0,s1); T->y = cvtpk(s2,s3);
}

__global__
__attribute__((amdgpu_flat_work_group_size(NTHR, NTHR)))
__attribute__((amdgpu_waves_per_eu(2, 2)))   // pin: LDS already caps at 1 blk/CU; unlock 256-reg budget
void cfm_kernel(const float* __restrict__ s_g,
                const float* __restrict__ a0_g,
                const int*   __restrict__ rad_g,
                const float* __restrict__ W1g, const float* __restrict__ b1g,
                const float* __restrict__ W2g, const float* __restrict__ b2g,
                const float* __restrict__ W3g, const float* __restrict__ b3g,
                float* __restrict__ out_g)
{
    extern __shared__ char lds[];
    const int tid  = threadIdx.x;
    const int lane = tid & 63;
    const int wv   = tid >> 6;     // 0..7
    const int c    = lane & 15;
    const int g    = lane >> 4;

    unsigned short* W1t = (unsigned short*)(lds + OFF_W1);
    unsigned short* W2t = (unsigned short*)(lds + OFF_W2);
    unsigned short* W3c = (unsigned short*)(lds + OFF_W3);
    float* W8L = (float*)(lds + OFF_W8);
    float* B2L = (float*)(lds + OFF_B2);

    // ---------------- stage shared weights ONCE (only barrier in the kernel) ----------------
    for (int idx = tid; idx < 128*128; idx += NTHR){
        int n = idx >> 7, k = idx & 127;
        if (k < 96)
            W1t[n*136 + k] = f2bf(k < 80 ? W1g[k*128 + n] : (k == 80 ? b1g[n] : 0.0f));
        W2t[n*136 + k] = f2bf(W2g[k*128 + n]);
    }
    for (int idx = tid; idx < 16*128; idx += NTHR){
        int m = idx >> 7, k = idx & 127;
        W3c[m*136 + k] = f2bf(W3g[k*32 + m] + W3g[k*32 + 16 + m]);
    }
    if (tid < 128)       W8L[tid]       = W1g[80*128 + tid];
    else if (tid < 256)  B2L[tid - 128] = b2g[tid - 128];
    __syncthreads();

    // per-lane LDS bases (in-loop = base + compile-time offset)
    const char* pW1  = lds + OFF_W1 + c*RB + g*16;
    const char* pW2  = lds + OFF_W2 + c*RB + g*16;
    const char* pW3  = lds + OFF_W3 + c*RB + g*16;
    char*       pWBw = lds + OFF_WB + wv*4352 + c*RB + g*8;
    const char* pWBr = lds + OFF_WB + wv*4352 + c*RB + g*16;
    const char* pW8  = lds + OFF_W8 + g*16;
    const char* pB2  = lds + OFF_B2 + g*16;

    // ---- register-cache all W2 A-fragments (wave-invariant, reused 64x) ----
    // 32 x s16x8 = 128 VGPRs. Eliminates the 32 ds_read_b128/step that were
    // 42% of the LDS read traffic on an LDS-pipe-bound kernel.
    s16x8 w2r[4][8];
#pragma unroll
    for (int p = 0; p < 4; ++p)
#pragma unroll
        for (int n2 = 0; n2 < 8; ++n2)
            w2r[p][n2] = *(const s16x8*)(pW2 + n2*4352 + p*64);

    f32x4 b3i;
    {
        f32x4 x0 = *(const f32x4*)(b3g + 4*g);
        f32x4 x1 = *(const f32x4*)(b3g + 16 + 4*g);
        b3i = x0 + x1;
    }

    // ---------------- two 128-row halves, weights persistent ----------------
    for (int half = 0; half < 2; ++half){
        const int row = blockIdx.x * (2*RPH) + half*RPH + wv*16 + c;

        // per-lane X fragments: k: a 0..15 | s 16..79 | 1.0 @80 | 0 81..95
        const float* srow = s_g + (size_t)row * 64;
        s16x8 xf0, xf1, xf2;
#pragma unroll
        for (int j = 0; j < 8; ++j) xf1[j] = (short)f2bf(srow[16 + 8*g + j]);
        if (g >= 2){
#pragma unroll
            for (int j = 0; j < 8; ++j) xf0[j] = (short)f2bf(srow[8*(g-2) + j]);
        }
        if (g < 2){
#pragma unroll
            for (int j = 0; j < 8; ++j) xf2[j] = (short)f2bf(srow[48 + 8*g + j]);
        } else {
#pragma unroll
            for (int j = 0; j < 8; ++j) xf2[j] = 0;
            if (g == 2) xf2[0] = (short)0x3F80;   // X[80] = 1.0 (feeds baked b1)
        }

        f32x4 av = *(const f32x4*)(a0_g + (size_t)row*16 + 4*g);
        float ldet = 0.0f;
        {
            unsigned d0 = cvtpk(av[0], av[1]), d1 = cvtpk(av[2], av[3]);
            int sA = (c + 32*g) & 63, sB = (c + 32*g + 16) & 63;
            unsigned w0 = __shfl(d0, sA, 64), w1 = __shfl(d1, sA, 64);
            unsigned w2 = __shfl(d0, sB, 64), w3 = __shfl(d1, sB, 64);
            if (g < 2){ u32x4 tv = {w0, w1, w2, w3}; xf0 = __builtin_bit_cast(s16x8, tv); }
        }

        const int* rpp = rad_g + ((size_t)row << 4) + 8*(g & 1);
        const int* rps = rad_g + ((size_t)row << 4) + 4*g;
        s16x8 pf;
        if (g < 2){
            i32x4 a = *(const i32x4*)rpp;
            i32x4 b = *(const i32x4*)(rpp + 4);
            pf = pconv(a, b);
        } else {
#pragma unroll
            for (int j = 0; j < 8; ++j) pf[j] = 0;
        }
        const int* rppN = rpp + (size_t)BATCH*16;

        for (int t = 0; t < NSTEP; ++t){
            const float tmid = ((float)t + 0.5f) * DELTA_F;

            i32x4 un0 = {0,0,0,0}, un1 = {0,0,0,0};
            if (g < 2 && t + 1 < NSTEP){
                un0 = *(const i32x4*)rppN;
                un1 = *(const i32x4*)(rppN + 4);
            }
            i32x4 us = *(const i32x4*)rps;

            f32x4 F[8], T[8];
#pragma unroll
            for (int n2 = 0; n2 < 8; ++n2){
                F[n2] = *(const f32x4*)(pB2 + n2*64);
                T[n2] = (f32x4){0,0,0,0};
            }

            // L1 chunk compute+pack+write (chunk p -> parity slot p&1)
            auto l1_chunk = [&](int p){
                const int po = (p & 1) << 7;
                s16x8 aA0 = *(const s16x8*)(pW1 + p*8704);
                s16x8 aB0 = *(const s16x8*)(pW1 + p*8704 + 4352);
                f32x4 w8a = *(const f32x4*)(pW8 + (2*p)*64);
                f32x4 w8b = *(const f32x4*)(pW8 + (2*p+1)*64);
                f32x4 hA = { tmid*w8a[0], tmid*w8a[1], tmid*w8a[2], tmid*w8a[3] };
                f32x4 hB = { tmid*w8b[0], tmid*w8b[1], tmid*w8b[2], tmid*w8b[3] };
                hA = mfma16(aA0, xf0, hA);
                hB = mfma16(aB0, xf0, hB);
                s16x8 aA1 = *(const s16x8*)(pW1 + p*8704 + 64);
                s16x8 aB1 = *(const s16x8*)(pW1 + p*8704 + 4352 + 64);
                hA = mfma16(aA1, xf1, hA);
                hB = mfma16(aB1, xf1, hB);
                s16x8 aA2 = *(const s16x8*)(pW1 + p*8704 + 128);
                s16x8 aB2 = *(const s16x8*)(pW1 + p*8704 + 4352 + 128);
                hA = mfma16(aA2, xf2, hA);
                hB = mfma16(aB2, xf2, hB);
                f32x4 z = {0,0,0,0};
                f32x4 tA = mfma16(aA0, pf, z);
                f32x4 tB = mfma16(aB0, pf, z);
                u32x2 HA, TA, HB, TB;
                relu_pack(hA, tA, &HA, &TA);
                relu_pack(hB, tB, &HB, &TB);
                *(u32x2*)(pWBw + po)      = HA;
                *(u32x2*)(pWBw + po + 32) = HB;
                *(u32x2*)(pWBw + po + 64) = TA;
                *(u32x2*)(pWBw + po + 96) = TB;
            };

            // ---- pipelined L1 -> L2: write chunk p+1, read chunk p (settled) ----
            __builtin_amdgcn_s_setprio(1);
            l1_chunk(0);
#pragma unroll
            for (int p = 0; p < 4; ++p){
                if (p < 3) l1_chunk(p + 1);
                const int po = (p & 1) << 7;
                s16x8 bh = *(const s16x8*)(pWBr + po);
                s16x8 bt = *(const s16x8*)(pWBr + po + 64);
#pragma unroll
                for (int n2 = 0; n2 < 8; ++n2){
                    F[n2] = mfma16(w2r[p][n2], bh, F[n2]);
                    T[n2] = mfma16(w2r[p][n2], bt, T[n2]);
                }
            }
            __builtin_amdgcn_s_setprio(0);

            // ---- pipelined L2 epilogue -> L3 (combined W3) ----
            auto l3_pack = [&](int e){
                const int po = (e & 1) << 7;
                u32x2 HA, TA, HB, TB;
                relu_pack(F[2*e],   T[2*e],   &HA, &TA);
                relu_pack(F[2*e+1], T[2*e+1], &HB, &TB);
                *(u32x2*)(pWBw + po)      = HA;
                *(u32x2*)(pWBw + po + 32) = HB;
                *(u32x2*)(pWBw + po + 64) = TA;
                *(u32x2*)(pWBw + po + 96) = TB;
            };
            f32x4 vf = b3i, vt = {0,0,0,0};
            l3_pack(0);
            __builtin_amdgcn_s_setprio(1);
#pragma unroll
            for (int e = 0; e < 4; ++e){
                if (e < 3) l3_pack(e + 1);
                const int po = (e & 1) << 7;
                s16x8 bh = *(const s16x8*)(pWBr + po);
                s16x8 bt = *(const s16x8*)(pWBr + po + 64);
                s16x8 w3 = *(const s16x8*)(pW3 + e*64);
                vf = mfma16(w3, bh, vf);
                vt = mfma16(w3, bt, vt);
            }
            __builtin_amdgcn_s_setprio(0);

            // ---- Euler update + X a-part refresh ----
            av[0] += DELTA_F * vf[0];
            av[1] += DELTA_F * vf[1];
            av[2] += DELTA_F * vf[2];
            av[3] += DELTA_F * vf[3];
            {
                unsigned d0 = cvtpk(av[0], av[1]), d1 = cvtpk(av[2], av[3]);
                int sA = (c + 32*g) & 63, sB = (c + 32*g + 16) & 63;
                unsigned w0 = __shfl(d0, sA, 64), w1 = __shfl(d1, sA, 64);
                unsigned w2 = __shfl(d0, sB, 64), w3 = __shfl(d1, sB, 64);
                if (g < 2){ u32x4 tv = {w0, w1, w2, w3}; xf0 = __builtin_bit_cast(s16x8, tv); }
            }

            // ---- Hutchinson div ----
            {
                int s0 = us[0] ? 0 : (int)0x80000000u;
                int s1 = us[1] ? 0 : (int)0x80000000u;
                int s2 = us[2] ? 0 : (int)0x80000000u;
                int s3 = us[3] ? 0 : (int)0x80000000u;
                float q0 = __int_as_float(__float_as_int(vt[0]) ^ s0);
                float q1 = __int_as_float(__float_as_int(vt[1]) ^ s1);
                float q2 = __int_as_float(__float_as_int(vt[2]) ^ s2);
                float q3 = __int_as_float(__float_as_int(vt[3]) ^ s3);
                float prod = (q0 + q1) + (q2 + q3);
                prod += __shfl_xor(prod, 16, 64);
                prod += __shfl_xor(prod, 32, 64);
                ldet -= DELTA_F * prod;
            }

            if (g < 2 && t + 1 < NSTEP) pf = pconv(un0, un1);
            rppN += (size_t)BATCH*16;
            rps  += (size_t)BATCH*16;
        }

        // ---- finalize this half (per-wave, no LDS, no barrier) ----
        float asq = av[0]*av[0] + av[1]*av[1] + av[2]*av[2] + av[3]*av[3];
        asq += __shfl_xor(asq, 16, 64);
        asq += __shfl_xor(asq, 32, 64);
        if (g == 0)
            out_g[row] = -0.5f*asq - 8.0f*LN2PI_F + ldet;
    }
}

extern "C" void kernel_launch(void* const* d_in, const int* in_sizes, int n_in,
                              void* d_out, int out_size, void* d_ws, size_t ws_size,
                              hipStream_t stream)
{
    const float* s_g  = (const float*)d_in[0];
    const float* a0_g = (const float*)d_in[1];
    const int*   rad  = (const int*)  d_in[2];
    const float* W1   = (const float*)d_in[3];
    const float* b1   = (const float*)d_in[4];
    const float* W2   = (const float*)d_in[5];
    const float* b2   = (const float*)d_in[6];
    const float* W3   = (const float*)d_in[7];
    const float* b3   = (const float*)d_in[8];
    float* out = (float*)d_out;

    // opt-in to >64KB dynamic LDS (host-side attribute; capture-safe)
    hipFuncSetAttribute(reinterpret_cast<const void*>(cfm_kernel),
                        hipFuncAttributeMaxDynamicSharedMemorySize, LDS_BYTES);

    cfm_kernel<<<BATCH/(2*RPH), NTHR, LDS_BYTES, stream>>>(
        s_g, a0_g, rad, W1, b1, W2, b2, W3, b3, out);
}

// Round 3
// 215.504 us; speedup vs baseline: 1.2077x; 1.2077x over previous
//
#include <hip/hip_runtime.h>
#include <hip/hip_bf16.h>
#include <stdint.h>

#define NSTEP   32
#define BATCH   65536
#define NTHR    512
#define RPB     256          /* rows per block = 8 waves x 32 */
#define DELTA_F (1.0f/32.0f)
#define LN2PI_F 1.83787706640934534f

// R22: full 32x32x16 MFMA rewrite.
//  - weight reads amortized over 32 batch rows/wave (2x fewer LDS reads per row)
//  - inter-layer transpose via v_permlane32_swap (VALU) -> WB LDS buffers DELETED
//  - b1 / t*W8 / b2 folded into extra bf16 K-channels (+bf16-residual channels)
//    -> no per-step W8/B2 LDS loads, h/F accumulators init via MFMA
//  - per wave-step: 68 ds_read_b128, 0 ds_write, 0 ds-shfl  (was ~152r+64w+shfl per 32 rows)
// Layouts (verified mappings): A[m][k]: m=l&31, k=8*(l>>5)+j ; B[k][n]: n=l&31, k=8*(l>>5)+j ;
// C/D: col=l&31, row=(r&3)+8*(r>>2)+4*(l>>5).
#define RB1 208              /* W1T row: 104 u16 (96 used: a0-15,s16-79,b1@80,W8@81,W8r@82,b1r@83) */
#define RB2 304              /* W2T row: 152 u16 (144 used: W2 0-127, b2@128, b2r@129) */
#define RB3 272              /* W3C row: 136 u16 (128 used; rows 16..31 zero) */
#define OFF_W1 0             /* 128*208 = 26624 */
#define OFF_W2 26624         /* 128*304 = 38912 */
#define OFF_W3 65536         /* 32*272  = 8704  */
#define LDS_BYTES 74240

typedef __attribute__((ext_vector_type(8)))  short    s16x8;
typedef __attribute__((ext_vector_type(8)))  __bf16   bf16x8;
typedef __attribute__((ext_vector_type(4)))  float    f32x4;
typedef __attribute__((ext_vector_type(16))) float    f32x16;
typedef __attribute__((ext_vector_type(4)))  int      i32x4;
typedef __attribute__((ext_vector_type(4)))  unsigned u32x4;

#define Z16 ((f32x16){0,0,0,0,0,0,0,0,0,0,0,0,0,0,0,0})

static __device__ __forceinline__ f32x16 mfma32(s16x8 a, s16x8 b, f32x16 c){
    return __builtin_amdgcn_mfma_f32_32x32x16_bf16(
        __builtin_bit_cast(bf16x8, a), __builtin_bit_cast(bf16x8, b), c, 0, 0, 0);
}

static __device__ __forceinline__ unsigned short f2bf(float f){
    union { float f; unsigned u; } v; v.f = f;
    unsigned u = v.u + 0x7fffu + ((v.u >> 16) & 1u);   // RNE
    return (unsigned short)(u >> 16);
}

static __device__ __forceinline__ float bf2f(unsigned short b){
    return __uint_as_float(((unsigned)b) << 16);
}

static __device__ __forceinline__ unsigned cvtpk(float lo, float hi){
    unsigned r;
    asm("v_cvt_pk_bf16_f32 %0, %1, %2" : "=v"(r) : "v"(lo), "v"(hi));
    return r;
}

// permlane32_swap: a' = [a_lo | b_lo], b' = [a_hi | b_hi]
static __device__ __forceinline__ void pswap(unsigned &a, unsigned &b){
    auto r = __builtin_amdgcn_permlane32_swap((int)a, (int)b, false, false);
    a = (unsigned)r[0]; b = (unsigned)r[1];
}

static __device__ __forceinline__ s16x8 pconv(i32x4 u0, i32x4 u1){
    const unsigned P = 0x3F80u, M = 0xBF80u;
    u32x4 d;
    d[0] = (u0[0] ? P : M) | ((u0[1] ? P : M) << 16);
    d[1] = (u0[2] ? P : M) | ((u0[3] ? P : M) << 16);
    d[2] = (u1[0] ? P : M) | ((u1[1] ? P : M) << 16);
    d[3] = (u1[2] ? P : M) | ((u1[3] ? P : M) << 16);
    return __builtin_bit_cast(s16x8, d);
}

// relu+mask pack of a 32x32 C-tile (16 f32) + tangent -> two k-tile B-frags each.
// P0..P7 = cvtpk(reg pairs); swap(P0,P2),(P1,P3) -> tile A slots; (P4,P6),(P5,P7) -> tile B.
static __device__ __forceinline__ void pack_tr(const f32x16 h, const f32x16 tt,
        s16x8* bA, s16x8* bB, s16x8* tA, s16x8* tB){
    unsigned Ph[8], Pt[8];
#pragma unroll
    for (int q = 0; q < 8; ++q){
        float h0 = h[2*q], h1 = h[2*q+1];
        float r0 = h0 > 0.f ? h0 : 0.f,      r1 = h1 > 0.f ? h1 : 0.f;
        float s0 = h0 > 0.f ? tt[2*q] : 0.f, s1 = h1 > 0.f ? tt[2*q+1] : 0.f;
        Ph[q] = cvtpk(r0, r1);
        Pt[q] = cvtpk(s0, s1);
    }
    pswap(Ph[0], Ph[2]); pswap(Ph[1], Ph[3]); pswap(Ph[4], Ph[6]); pswap(Ph[5], Ph[7]);
    pswap(Pt[0], Pt[2]); pswap(Pt[1], Pt[3]); pswap(Pt[4], Pt[6]); pswap(Pt[5], Pt[7]);
    *bA = __builtin_bit_cast(s16x8, (u32x4){Ph[0], Ph[1], Ph[2], Ph[3]});
    *bB = __builtin_bit_cast(s16x8, (u32x4){Ph[4], Ph[5], Ph[6], Ph[7]});
    *tA = __builtin_bit_cast(s16x8, (u32x4){Pt[0], Pt[1], Pt[2], Pt[3]});
    *tB = __builtin_bit_cast(s16x8, (u32x4){Pt[4], Pt[5], Pt[6], Pt[7]});
}

__global__ __launch_bounds__(NTHR, 2)
void cfm_kernel(const float* __restrict__ s_g,
                const float* __restrict__ a0_g,
                const int*   __restrict__ rad_g,
                const float* __restrict__ W1g, const float* __restrict__ b1g,
                const float* __restrict__ W2g, const float* __restrict__ b2g,
                const float* __restrict__ W3g, const float* __restrict__ b3g,
                float* __restrict__ out_g)
{
    extern __shared__ char lds[];
    const int tid  = threadIdx.x;
    const int lane = tid & 63;
    const int wv   = tid >> 6;     // 0..7
    const int c32  = lane & 31;    // batch col within wave tile
    const int hi   = lane >> 5;    // k-half

    unsigned short* W1t = (unsigned short*)(lds + OFF_W1);
    unsigned short* W2t = (unsigned short*)(lds + OFF_W2);
    unsigned short* W3c = (unsigned short*)(lds + OFF_W3);

    // ---------------- stage weights ONCE (only barrier in kernel) ----------------
    for (int idx = tid; idx < 128*104; idx += NTHR){
        int n = idx / 104, k = idx % 104;
        float v = 0.f;
        if (k < 80)       v = W1g[k*128 + n];
        else if (k == 80) v = b1g[n];
        else if (k == 81) v = W1g[80*128 + n];
        else if (k == 82){ float w = W1g[80*128 + n]; v = w - bf2f(f2bf(w)); }
        else if (k == 83){ float bb = b1g[n];         v = bb - bf2f(f2bf(bb)); }
        W1t[n*104 + k] = f2bf(v);
    }
    for (int idx = tid; idx < 128*152; idx += NTHR){
        int n = idx / 152, k = idx % 152;
        float v = 0.f;
        if (k < 128)       v = W2g[k*128 + n];
        else if (k == 128) v = b2g[n];
        else if (k == 129){ float bb = b2g[n]; v = bb - bf2f(f2bf(bb)); }
        W2t[n*152 + k] = f2bf(v);
    }
    for (int idx = tid; idx < 32*136; idx += NTHR){
        int m = idx / 136, k = idx % 136;
        float v = (m < 16 && k < 128) ? (W3g[k*32 + m] + W3g[k*32 + 16 + m]) : 0.f;
        W3c[m*136 + k] = f2bf(v);
    }
    __syncthreads();

    // per-lane LDS bases (A-operand rows = c32; +hi*16 = k-half)
    const char* pW1 = lds + OFF_W1 + c32*RB1 + hi*16;
    const char* pW2 = lds + OFF_W2 + c32*RB2 + hi*16;
    const char* pW3 = lds + OFF_W3 + c32*RB3 + hi*16;

    const int row = blockIdx.x * RPB + wv*32 + c32;

    // ---- X s-tiles (static over steps): tile K holds x[16K+8hi+j] ----
    const float* srow = s_g + (size_t)row * 64;
    s16x8 xk1, xk2, xk3, xk4;
    {
        auto mk_s = [&](int K)->s16x8{
            f32x4 u = *(const f32x4*)(srow + 16*(K-1) + 8*hi);
            f32x4 w = *(const f32x4*)(srow + 16*(K-1) + 8*hi + 4);
            return __builtin_bit_cast(s16x8, (u32x4){
                cvtpk(u[0],u[1]), cvtpk(u[2],u[3]), cvtpk(w[0],w[1]), cvtpk(w[2],w[3])});
        };
        xk1 = mk_s(1); xk2 = mk_s(2); xk3 = mk_s(3); xk4 = mk_s(4);
    }

    // a in f32: av0 = a[4hi+j], av1 = a[8+4hi+j]  (matches C-layout rows r0..3 / r4..7)
    f32x4 av0 = *(const f32x4*)(a0_g + (size_t)row*16 + 4*hi);
    f32x4 av1 = *(const f32x4*)(a0_g + (size_t)row*16 + 8 + 4*hi);

    // xk0 (a-tile B-frag) from av via cvtpk + permlane32_swap
    auto mk_a = [&]()->s16x8{
        unsigned A0 = cvtpk(av0[0],av0[1]), A1 = cvtpk(av0[2],av0[3]);
        unsigned B0 = cvtpk(av1[0],av1[1]), B1 = cvtpk(av1[2],av1[3]);
        pswap(A0, B0); pswap(A1, B1);
        return __builtin_bit_cast(s16x8, (u32x4){A0, A1, B0, B1});
    };
    s16x8 xk0 = mk_a();

    // b3 combined (v_c + r), f32 per-lane: rows {4hi+j} and {8+4hi+j}
    f32x4 b3c0, b3c1;
    {
        f32x4 p0 = *(const f32x4*)(b3g + 4*hi);
        f32x4 p1 = *(const f32x4*)(b3g + 16 + 4*hi);
        f32x4 p2 = *(const f32x4*)(b3g + 8 + 4*hi);
        f32x4 p3 = *(const f32x4*)(b3g + 24 + 4*hi);
        b3c0 = p0 + p1; b3c1 = p2 + p3;
    }

    // rad: pf (JVP direction B-frag) dims 8hi+j ; us (Hutchinson signs) dims {4hi+j, 8+4hi+j}
    const int* rp = rad_g + ((size_t)row << 4);
    s16x8 pf;
    {
        i32x4 a = *(const i32x4*)(rp + 8*hi);
        i32x4 b = *(const i32x4*)(rp + 8*hi + 4);
        pf = pconv(a, b);
    }

    float ldet = 0.0f;

    for (int t = 0; t < NSTEP; ++t){
        const float tmid = ((float)t + 0.5f) * DELTA_F;
        const int* rpN = rp + (size_t)BATCH*16;

        // prefetch next step's direction ints; load this step's sign ints
        i32x4 pn0 = {0,0,0,0}, pn1 = {0,0,0,0};
        if (t + 1 < NSTEP){
            pn0 = *(const i32x4*)(rpN + 8*hi);
            pn1 = *(const i32x4*)(rpN + 8*hi + 4);
        }
        i32x4 us0 = *(const i32x4*)(rp + 4*hi);
        i32x4 us1 = *(const i32x4*)(rp + 8 + 4*hi);

        // const/time tile: k80=1(b1), k81=tmid(W8), k82=tmid(W8res), k83=1(b1res); hi=1 all 0
        s16x8 xk5;
        {
            unsigned tb = (unsigned)f2bf(tmid);          // exact in bf16
            unsigned s0 = hi ? 0u : (0x3F80u | (tb << 16));
            unsigned s1 = hi ? 0u : (tb | (0x3F80u << 16));
            xk5 = __builtin_bit_cast(s16x8, (u32x4){s0, s1, 0u, 0u});
        }

        // ---- F init via b2 k-tile (K2=8); T zero ----
        f32x16 F[4], T[4];
        {
            unsigned b8 = hi ? 0u : 0x3F803F80u;         // (1.0,1.0) @ k=128,129
            s16x8 bb = __builtin_bit_cast(s16x8, (u32x4){b8, 0u, 0u, 0u});
#pragma unroll
            for (int Mo = 0; Mo < 4; ++Mo){
                s16x8 w28 = *(const s16x8*)(pW2 + Mo*9728 + 8*32);
                F[Mo] = mfma32(w28, bb, Z16);
                T[Mo] = Z16;
            }
        }

        __builtin_amdgcn_s_setprio(1);
        // ---- fused L1 chunk -> permlane transpose -> L2 accumulate ----
#pragma unroll
        for (int M = 0; M < 4; ++M){
            s16x8 w10 = *(const s16x8*)(pW1 + M*6656);
            f32x16 h  = mfma32(w10, xk0, Z16);
            f32x16 tt = mfma32(w10, pf,  Z16);
            h = mfma32(*(const s16x8*)(pW1 + M*6656 +  32), xk1, h);
            h = mfma32(*(const s16x8*)(pW1 + M*6656 +  64), xk2, h);
            h = mfma32(*(const s16x8*)(pW1 + M*6656 +  96), xk3, h);
            h = mfma32(*(const s16x8*)(pW1 + M*6656 + 128), xk4, h);
            h = mfma32(*(const s16x8*)(pW1 + M*6656 + 160), xk5, h);

            s16x8 bhA, bhB, btA, btB;
            pack_tr(h, tt, &bhA, &bhB, &btA, &btB);
#pragma unroll
            for (int Mo = 0; Mo < 4; ++Mo){
                s16x8 w2a = *(const s16x8*)(pW2 + Mo*9728 + (2*M)*32);
                F[Mo] = mfma32(w2a, bhA, F[Mo]);
                T[Mo] = mfma32(w2a, btA, T[Mo]);
                s16x8 w2b = *(const s16x8*)(pW2 + Mo*9728 + (2*M+1)*32);
                F[Mo] = mfma32(w2b, bhB, F[Mo]);
                T[Mo] = mfma32(w2b, btB, T[Mo]);
            }
        }

        // ---- L3 (W3 combined; rows 16..31 of A are zero -> acc r8..15 unused) ----
        f32x16 vf = {b3c0[0], b3c0[1], b3c0[2], b3c0[3],
                     b3c1[0], b3c1[1], b3c1[2], b3c1[3],
                     0,0,0,0,0,0,0,0};
        f32x16 vt = Z16;
#pragma unroll
        for (int M = 0; M < 4; ++M){
            s16x8 qhA, qhB, qtA, qtB;
            pack_tr(F[M], T[M], &qhA, &qhB, &qtA, &qtB);
            s16x8 w3a = *(const s16x8*)(pW3 + (2*M)*32);
            vf = mfma32(w3a, qhA, vf);
            vt = mfma32(w3a, qtA, vt);
            s16x8 w3b = *(const s16x8*)(pW3 + (2*M+1)*32);
            vf = mfma32(w3b, qhB, vf);
            vt = mfma32(w3b, qtB, vt);
        }
        __builtin_amdgcn_s_setprio(0);

        // ---- Euler update (r0..3 -> dims 4hi+j, r4..7 -> dims 8+4hi+j) ----
        av0[0] += DELTA_F * vf[0]; av0[1] += DELTA_F * vf[1];
        av0[2] += DELTA_F * vf[2]; av0[3] += DELTA_F * vf[3];
        av1[0] += DELTA_F * vf[4]; av1[1] += DELTA_F * vf[5];
        av1[2] += DELTA_F * vf[6]; av1[3] += DELTA_F * vf[7];
        xk0 = mk_a();

        // ---- Hutchinson: prod = sum_d (+/- jv[d]), halves summed via permlane swap ----
        {
            int g0 = us0[0] ? 0 : (int)0x80000000u;
            int g1 = us0[1] ? 0 : (int)0x80000000u;
            int g2 = us0[2] ? 0 : (int)0x80000000u;
            int g3 = us0[3] ? 0 : (int)0x80000000u;
            int g4 = us1[0] ? 0 : (int)0x80000000u;
            int g5 = us1[1] ? 0 : (int)0x80000000u;
            int g6 = us1[2] ? 0 : (int)0x80000000u;
            int g7 = us1[3] ? 0 : (int)0x80000000u;
            float q0 = __int_as_float(__float_as_int(vf[0]*0.f + vt[0]) ^ g0);
            float q1 = __int_as_float(__float_as_int(vt[1]) ^ g1);
            float q2 = __int_as_float(__float_as_int(vt[2]) ^ g2);
            float q3 = __int_as_float(__float_as_int(vt[3]) ^ g3);
            float q4 = __int_as_float(__float_as_int(vt[4]) ^ g4);
            float q5 = __int_as_float(__float_as_int(vt[5]) ^ g5);
            float q6 = __int_as_float(__float_as_int(vt[6]) ^ g6);
            float q7 = __int_as_float(__float_as_int(vt[7]) ^ g7);
            float prod = ((q0 + q1) + (q2 + q3)) + ((q4 + q5) + (q6 + q7));
            unsigned pu = __float_as_uint(prod), pv = pu;
            pswap(pu, pv);                       // pu=[lo,lo], pv=[hi,hi]
            prod = __uint_as_float(pu) + __uint_as_float(pv);
            ldet -= DELTA_F * prod;
        }

        pf = pconv(pn0, pn1);
        rp = rpN;
    }

    // ---- finalize: logp = -0.5*|a|^2 - 8*ln(2pi) + ldet ----
    float asq = av0[0]*av0[0] + av0[1]*av0[1] + av0[2]*av0[2] + av0[3]*av0[3]
              + av1[0]*av1[0] + av1[1]*av1[1] + av1[2]*av1[2] + av1[3]*av1[3];
    {
        unsigned pu = __float_as_uint(asq), pv = pu;
        pswap(pu, pv);
        asq = __uint_as_float(pu) + __uint_as_float(pv);
    }
    if (hi == 0)
        out_g[row] = -0.5f*asq - 8.0f*LN2PI_F + ldet;
}

extern "C" void kernel_launch(void* const* d_in, const int* in_sizes, int n_in,
                              void* d_out, int out_size, void* d_ws, size_t ws_size,
                              hipStream_t stream)
{
    const float* s_g  = (const float*)d_in[0];
    const float* a0_g = (const float*)d_in[1];
    const int*   rad  = (const int*)  d_in[2];
    const float* W1   = (const float*)d_in[3];
    const float* b1   = (const float*)d_in[4];
    const float* W2   = (const float*)d_in[5];
    const float* b2   = (const float*)d_in[6];
    const float* W3   = (const float*)d_in[7];
    const float* b3   = (const float*)d_in[8];
    float* out = (float*)d_out;

    // opt-in to >64KB dynamic LDS (host-side attribute; capture-safe)
    hipFuncSetAttribute(reinterpret_cast<const void*>(cfm_kernel),
                        hipFuncAttributeMaxDynamicSharedMemorySize, LDS_BYTES);

    cfm_kernel<<<BATCH/RPB, NTHR, LDS_BYTES, stream>>>(
        s_g, a0_g, rad, W1, b1, W2, b2, W3, b3, out);
}